// Round 1
// baseline (1418.635 us; speedup 1.0000x reference)
//
#include <hip/hip_runtime.h>

#define DIM 128

// -------------------- GEMM: support = X @ W --------------------
// Block = 256 threads, computes 32 rows x 128 cols. W (128x128 fp32 = 64KB) in LDS.
// Thread t: row = t>>3, col-group = t&7 (16 cols = 4 float4 accumulators).
__global__ __launch_bounds__(256) void gemm_xw(const float* __restrict__ X,
                                               const float* __restrict__ W,
                                               float* __restrict__ S,
                                               int n_nodes) {
    __shared__ float4 wlds[DIM * (DIM / 4)];  // 128 rows x 32 float4 = 64 KB

    const float4* W4 = (const float4*)W;
    for (int i = threadIdx.x; i < DIM * (DIM / 4); i += 256) wlds[i] = W4[i];
    __syncthreads();

    const int row = blockIdx.x * 32 + (threadIdx.x >> 3);
    const int colg = threadIdx.x & 7;  // 8 groups x 16 cols
    if (row >= n_nodes) return;

    const float4* Xr = (const float4*)(X + (size_t)row * DIM);

    float acc[16];
#pragma unroll
    for (int i = 0; i < 16; ++i) acc[i] = 0.0f;

    for (int k4 = 0; k4 < DIM / 4; ++k4) {
        const float4 xv = Xr[k4];
        const float xs[4] = {xv.x, xv.y, xv.z, xv.w};
#pragma unroll
        for (int kk = 0; kk < 4; ++kk) {
            const int k = k4 * 4 + kk;
            const float x = xs[kk];
            const float4* wr = &wlds[k * (DIM / 4) + colg * 4];
#pragma unroll
            for (int c = 0; c < 4; ++c) {
                const float4 wv = wr[c];
                acc[c * 4 + 0] = fmaf(x, wv.x, acc[c * 4 + 0]);
                acc[c * 4 + 1] = fmaf(x, wv.y, acc[c * 4 + 1]);
                acc[c * 4 + 2] = fmaf(x, wv.z, acc[c * 4 + 2]);
                acc[c * 4 + 3] = fmaf(x, wv.w, acc[c * 4 + 3]);
            }
        }
    }

    float4* Sr = (float4*)(S + (size_t)row * DIM) + colg * 4;
#pragma unroll
    for (int c = 0; c < 4; ++c) {
        float4 v;
        v.x = acc[c * 4 + 0];
        v.y = acc[c * 4 + 1];
        v.z = acc[c * 4 + 2];
        v.w = acc[c * 4 + 3];
        Sr[c] = v;
    }
}

// -------------------- init: out[n][j] = bias[j] --------------------
__global__ __launch_bounds__(256) void init_bias(const float* __restrict__ bias,
                                                 float* __restrict__ out,
                                                 int total4) {  // n_nodes * 32 float4s
    const int idx = blockIdx.x * 256 + threadIdx.x;
    if (idx < total4) {
        ((float4*)out)[idx] = ((const float4*)bias)[idx & (DIM / 4 - 1)];
    }
}

// -------------------- scatter: out[dst] += ew * support[src] --------------------
// 64 lanes per edge, float2 per lane -> 2 fp32 HW atomics per lane.
__global__ __launch_bounds__(256) void edge_scatter(const float* __restrict__ S,
                                                    const float* __restrict__ ew,
                                                    const int* __restrict__ src,
                                                    const int* __restrict__ dst,
                                                    float* __restrict__ out,
                                                    int n_edges) {
    const int e = blockIdx.x * 4 + (threadIdx.x >> 6);
    if (e >= n_edges) return;
    const int lane = threadIdx.x & 63;

    const int s = src[e];
    const int d = dst[e];
    const float w = ew[e];

    const float2 sv = ((const float2*)(S + (size_t)s * DIM))[lane];
    float* op = out + (size_t)d * DIM + lane * 2;
    unsafeAtomicAdd(op + 0, sv.x * w);
    unsafeAtomicAdd(op + 1, sv.y * w);
}

extern "C" void kernel_launch(void* const* d_in, const int* in_sizes, int n_in,
                              void* d_out, int out_size, void* d_ws, size_t ws_size,
                              hipStream_t stream) {
    const float* X    = (const float*)d_in[0];
    const float* W    = (const float*)d_in[1];
    const float* bias = (const float*)d_in[2];
    const float* ew   = (const float*)d_in[3];
    const int*   src  = (const int*)d_in[4];
    const int*   dst  = (const int*)d_in[5];
    float* out = (float*)d_out;
    float* S   = (float*)d_ws;  // support = X@W, n_nodes*128 fp32 (51.2 MB)

    const int n_nodes = in_sizes[0] / DIM;
    const int n_edges = in_sizes[3];

    gemm_xw<<<(n_nodes + 31) / 32, 256, 0, stream>>>(X, W, S, n_nodes);

    const int total4 = n_nodes * (DIM / 4);
    init_bias<<<(total4 + 255) / 256, 256, 0, stream>>>(bias, out, total4);

    edge_scatter<<<(n_edges + 3) / 4, 256, 0, stream>>>(S, ew, src, dst, out, n_edges);
}

// Round 4
// 564.033 us; speedup vs baseline: 2.5152x; 2.5152x over previous
//
#include <hip/hip_runtime.h>

#define DIM 128

// -------------------- GEMM: support = X @ W --------------------
__global__ __launch_bounds__(256) void gemm_xw(const float* __restrict__ X,
                                               const float* __restrict__ W,
                                               float* __restrict__ S,
                                               int n_nodes) {
    __shared__ float4 wlds[DIM * (DIM / 4)];  // 64 KB

    const float4* W4 = (const float4*)W;
    for (int i = threadIdx.x; i < DIM * (DIM / 4); i += 256) wlds[i] = W4[i];
    __syncthreads();

    const int row = blockIdx.x * 32 + (threadIdx.x >> 3);
    const int colg = threadIdx.x & 7;
    if (row >= n_nodes) return;

    const float4* Xr = (const float4*)(X + (size_t)row * DIM);

    float acc[16];
#pragma unroll
    for (int i = 0; i < 16; ++i) acc[i] = 0.0f;

    for (int k4 = 0; k4 < DIM / 4; ++k4) {
        const float4 xv = Xr[k4];
        const float xs[4] = {xv.x, xv.y, xv.z, xv.w};
#pragma unroll
        for (int kk = 0; kk < 4; ++kk) {
            const int k = k4 * 4 + kk;
            const float x = xs[kk];
            const float4* wr = &wlds[k * (DIM / 4) + colg * 4];
#pragma unroll
            for (int c = 0; c < 4; ++c) {
                const float4 wv = wr[c];
                acc[c * 4 + 0] = fmaf(x, wv.x, acc[c * 4 + 0]);
                acc[c * 4 + 1] = fmaf(x, wv.y, acc[c * 4 + 1]);
                acc[c * 4 + 2] = fmaf(x, wv.z, acc[c * 4 + 2]);
                acc[c * 4 + 3] = fmaf(x, wv.w, acc[c * 4 + 3]);
            }
        }
    }

    float4* Sr = (float4*)(S + (size_t)row * DIM) + colg * 4;
#pragma unroll
    for (int c = 0; c < 4; ++c) {
        float4 v = {acc[c * 4 + 0], acc[c * 4 + 1], acc[c * 4 + 2], acc[c * 4 + 3]};
        Sr[c] = v;
    }
}

// -------------------- CSR build --------------------
__global__ __launch_bounds__(256) void zero_ints(int* __restrict__ p, int n) {
    const int i = blockIdx.x * 256 + threadIdx.x;
    if (i < n) p[i] = 0;
}

__global__ __launch_bounds__(256) void hist_dst(const int* __restrict__ dst,
                                                int* __restrict__ counts,
                                                int n_edges) {
    for (int e = blockIdx.x * 256 + threadIdx.x; e < n_edges; e += gridDim.x * 256)
        atomicAdd(&counts[dst[e]], 1);
}

#define SCAN_B 1024
// Per-block exclusive scan of counts -> offsets (local), block totals -> bsum.
__global__ __launch_bounds__(SCAN_B) void scan_block(const int* __restrict__ counts,
                                                     int* __restrict__ offsets,
                                                     int* __restrict__ bsum,
                                                     int n) {
    __shared__ int lds[SCAN_B];
    const int i = blockIdx.x * SCAN_B + threadIdx.x;
    int v = (i < n) ? counts[i] : 0;
    const int own = v;
    lds[threadIdx.x] = v;
    __syncthreads();
#pragma unroll
    for (int off = 1; off < SCAN_B; off <<= 1) {
        int t = (threadIdx.x >= off) ? lds[threadIdx.x - off] : 0;
        __syncthreads();
        lds[threadIdx.x] += t;
        __syncthreads();
    }
    if (i < n) offsets[i] = lds[threadIdx.x] - own;  // exclusive
    if (threadIdx.x == SCAN_B - 1) bsum[blockIdx.x] = lds[threadIdx.x];
}

// Single-thread exclusive scan of block sums (~98 blocks here).
__global__ void scan_tops(int* __restrict__ bsum, int nblocks) {
    if (threadIdx.x == 0 && blockIdx.x == 0) {
        int run = 0;
        for (int b = 0; b < nblocks && b < SCAN_B; ++b) {
            int v = bsum[b];
            bsum[b] = run;
            run += v;
        }
    }
}

// Add block prefix; also initialize cursor = final offsets.
__global__ __launch_bounds__(SCAN_B) void scan_fix(int* __restrict__ offsets,
                                                   const int* __restrict__ bsum,
                                                   int* __restrict__ cursor,
                                                   int n) {
    const int i = blockIdx.x * SCAN_B + threadIdx.x;
    if (i < n) {
        const int v = offsets[i] + bsum[blockIdx.x];
        offsets[i] = v;
        cursor[i] = v;
    }
}

__global__ __launch_bounds__(256) void bucket_edges(const int* __restrict__ dst,
                                                    int* __restrict__ cursor,
                                                    int* __restrict__ perm,
                                                    int n_edges) {
    for (int e = blockIdx.x * 256 + threadIdx.x; e < n_edges; e += gridDim.x * 256) {
        const int pos = atomicAdd(&cursor[dst[e]], 1);
        perm[pos] = e;
    }
}

// -------------------- reduce: out[n] = bias + sum_{e in csr[n]} ew[e]*S[src[e]] ------
// One wave (64 lanes) per node; lane holds float2 accumulator.
__global__ __launch_bounds__(256) void gcn_reduce(const float* __restrict__ S,
                                                  const float* __restrict__ ew,
                                                  const int* __restrict__ src,
                                                  const int* __restrict__ perm,
                                                  const int* __restrict__ offsets,
                                                  const float* __restrict__ bias,
                                                  float* __restrict__ out,
                                                  int n_nodes, int n_edges) {
    const int node = blockIdx.x * 4 + (threadIdx.x >> 6);
    if (node >= n_nodes) return;
    const int lane = threadIdx.x & 63;

    const int start = offsets[node];
    const int end = (node + 1 < n_nodes) ? offsets[node + 1] : n_edges;

    float2 acc = ((const float2*)bias)[lane];

    for (int i = start; i < end; ++i) {
        const int e = perm[i];
        const int s = src[e];
        const float w = ew[e];
        const float2 sv = ((const float2*)(S + (size_t)s * DIM))[lane];
        acc.x = fmaf(w, sv.x, acc.x);
        acc.y = fmaf(w, sv.y, acc.y);
    }

    ((float2*)(out + (size_t)node * DIM))[lane] = acc;
}

extern "C" void kernel_launch(void* const* d_in, const int* in_sizes, int n_in,
                              void* d_out, int out_size, void* d_ws, size_t ws_size,
                              hipStream_t stream) {
    const float* X    = (const float*)d_in[0];
    const float* W    = (const float*)d_in[1];
    const float* bias = (const float*)d_in[2];
    const float* ew   = (const float*)d_in[3];
    const int*   src  = (const int*)d_in[4];
    const int*   dst  = (const int*)d_in[5];
    float* out = (float*)d_out;

    const int n_nodes = in_sizes[0] / DIM;
    const int n_edges = in_sizes[3];

    // Workspace layout (bytes from d_ws):
    char* ws = (char*)d_ws;
    float* S      = (float*)ws;                                  // 51.2 MB
    int* counts   = (int*)(ws + (size_t)n_nodes * DIM * 4);      // 400 KB
    int* offsets  = counts + n_nodes;                            // 400 KB
    int* cursor   = offsets + n_nodes;                           // 400 KB
    int* bsum     = cursor + n_nodes;                            // 4 KB
    int* perm     = bsum + SCAN_B;                               // 6.4 MB

    // 1. GEMM
    gemm_xw<<<(n_nodes + 31) / 32, 256, 0, stream>>>(X, W, S, n_nodes);

    // 2. CSR build
    zero_ints<<<(n_nodes + 255) / 256, 256, 0, stream>>>(counts, n_nodes);
    hist_dst<<<2048, 256, 0, stream>>>(dst, counts, n_edges);

    const int nblocks = (n_nodes + SCAN_B - 1) / SCAN_B;
    scan_block<<<nblocks, SCAN_B, 0, stream>>>(counts, offsets, bsum, n_nodes);
    scan_tops<<<1, 64, 0, stream>>>(bsum, nblocks);
    scan_fix<<<nblocks, SCAN_B, 0, stream>>>(offsets, bsum, cursor, n_nodes);

    bucket_edges<<<2048, 256, 0, stream>>>(dst, cursor, perm, n_edges);

    // 3. Per-node reduction (bias fused, single non-atomic write)
    gcn_reduce<<<(n_nodes + 3) / 4, 256, 0, stream>>>(S, ew, src, perm, offsets,
                                                      bias, out, n_nodes, n_edges);
}

// Round 5
// 370.846 us; speedup vs baseline: 3.8254x; 1.5209x over previous
//
#include <hip/hip_runtime.h>
#include <hip/hip_bf16.h>

#define DIM 128

// -------------------- GEMM: support = X @ W, stored as bf16 --------------------
__global__ __launch_bounds__(256) void gemm_xw(const float* __restrict__ X,
                                               const float* __restrict__ W,
                                               __hip_bfloat162* __restrict__ S2,
                                               int n_nodes) {
    __shared__ float4 wlds[DIM * (DIM / 4)];  // 64 KB

    const float4* W4 = (const float4*)W;
    for (int i = threadIdx.x; i < DIM * (DIM / 4); i += 256) wlds[i] = W4[i];
    __syncthreads();

    const int row = blockIdx.x * 32 + (threadIdx.x >> 3);
    const int colg = threadIdx.x & 7;
    if (row >= n_nodes) return;

    const float4* Xr = (const float4*)(X + (size_t)row * DIM);

    float acc[16];
#pragma unroll
    for (int i = 0; i < 16; ++i) acc[i] = 0.0f;

    for (int k4 = 0; k4 < DIM / 4; ++k4) {
        const float4 xv = Xr[k4];
        const float xs[4] = {xv.x, xv.y, xv.z, xv.w};
#pragma unroll
        for (int kk = 0; kk < 4; ++kk) {
            const int k = k4 * 4 + kk;
            const float x = xs[kk];
            const float4* wr = &wlds[k * (DIM / 4) + colg * 4];
#pragma unroll
            for (int c = 0; c < 4; ++c) {
                const float4 wv = wr[c];
                acc[c * 4 + 0] = fmaf(x, wv.x, acc[c * 4 + 0]);
                acc[c * 4 + 1] = fmaf(x, wv.y, acc[c * 4 + 1]);
                acc[c * 4 + 2] = fmaf(x, wv.z, acc[c * 4 + 2]);
                acc[c * 4 + 3] = fmaf(x, wv.w, acc[c * 4 + 3]);
            }
        }
    }

    // Store 16 cols as 8 bf16x2 (cols colg*16 .. colg*16+15)
    __hip_bfloat162* Sr = S2 + (size_t)row * (DIM / 2) + colg * 8;
#pragma unroll
    for (int c = 0; c < 8; ++c) {
        float2 f = {acc[2 * c], acc[2 * c + 1]};
        Sr[c] = __float22bfloat162_rn(f);
    }
}

// -------------------- CSR build --------------------
__global__ __launch_bounds__(256) void zero_ints(int* __restrict__ p, int n) {
    const int i = blockIdx.x * 256 + threadIdx.x;
    if (i < n) p[i] = 0;
}

__global__ __launch_bounds__(256) void hist_dst(const int* __restrict__ dst,
                                                int* __restrict__ counts,
                                                int n_edges) {
    for (int e = blockIdx.x * 256 + threadIdx.x; e < n_edges; e += gridDim.x * 256)
        atomicAdd(&counts[dst[e]], 1);
}

#define SCAN_B 1024
__global__ __launch_bounds__(SCAN_B) void scan_block(const int* __restrict__ counts,
                                                     int* __restrict__ offsets,
                                                     int* __restrict__ bsum,
                                                     int n) {
    __shared__ int lds[SCAN_B];
    const int i = blockIdx.x * SCAN_B + threadIdx.x;
    int v = (i < n) ? counts[i] : 0;
    const int own = v;
    lds[threadIdx.x] = v;
    __syncthreads();
#pragma unroll
    for (int off = 1; off < SCAN_B; off <<= 1) {
        int t = (threadIdx.x >= off) ? lds[threadIdx.x - off] : 0;
        __syncthreads();
        lds[threadIdx.x] += t;
        __syncthreads();
    }
    if (i < n) offsets[i] = lds[threadIdx.x] - own;  // exclusive
    if (threadIdx.x == SCAN_B - 1) bsum[blockIdx.x] = lds[threadIdx.x];
}

// Parallel exclusive scan of block sums (single block; nblocks <= 1024).
__global__ __launch_bounds__(SCAN_B) void scan_tops(int* __restrict__ bsum, int nblocks) {
    __shared__ int lds[SCAN_B];
    int v = (threadIdx.x < nblocks) ? bsum[threadIdx.x] : 0;
    const int own = v;
    lds[threadIdx.x] = v;
    __syncthreads();
#pragma unroll
    for (int off = 1; off < SCAN_B; off <<= 1) {
        int t = (threadIdx.x >= off) ? lds[threadIdx.x - off] : 0;
        __syncthreads();
        lds[threadIdx.x] += t;
        __syncthreads();
    }
    if (threadIdx.x < nblocks) bsum[threadIdx.x] = lds[threadIdx.x] - own;
}

__global__ __launch_bounds__(SCAN_B) void scan_fix(int* __restrict__ offsets,
                                                   const int* __restrict__ bsum,
                                                   int* __restrict__ cursor,
                                                   int n) {
    const int i = blockIdx.x * SCAN_B + threadIdx.x;
    if (i < n) {
        const int v = offsets[i] + bsum[blockIdx.x];
        offsets[i] = v;
        cursor[i] = v;
    }
}

// Bucket edges by dst, materializing {src, weight-bits} in sorted position —
// removes one level of indirection from the reduce's dependent-load chain.
__global__ __launch_bounds__(256) void bucket_edges(const int* __restrict__ dst,
                                                    const int* __restrict__ src,
                                                    const float* __restrict__ ew,
                                                    int* __restrict__ cursor,
                                                    int2* __restrict__ edge_sw,
                                                    int n_edges) {
    for (int e = blockIdx.x * 256 + threadIdx.x; e < n_edges; e += gridDim.x * 256) {
        const int pos = atomicAdd(&cursor[dst[e]], 1);
        edge_sw[pos] = make_int2(src[e], __float_as_int(ew[e]));
    }
}

// -------------------- reduce: out[n] = bias + sum ew*S[src] --------------------
// One wave per node. Lane l preloads edge (start+l)'s {src,w} (coalesced), inner
// loop broadcasts via shfl; 4x unroll keeps 4 independent S-row gathers in flight.
__global__ __launch_bounds__(256) void gcn_reduce(const __hip_bfloat162* __restrict__ S2,
                                                  const int2* __restrict__ edge_sw,
                                                  const int* __restrict__ offsets,
                                                  const float* __restrict__ bias,
                                                  float* __restrict__ out,
                                                  int n_nodes, int n_edges) {
    const int node = blockIdx.x * 4 + (threadIdx.x >> 6);
    if (node >= n_nodes) return;
    const int lane = threadIdx.x & 63;

    const int start = offsets[node];
    const int end = (node + 1 < n_nodes) ? offsets[node + 1] : n_edges;

    float2 acc = ((const float2*)bias)[lane];

    for (int base = start; base < end; base += 64) {
        const int cnt = min(64, end - base);
        int2 meta = make_int2(0, 0);
        if (lane < cnt) meta = edge_sw[base + lane];

        int i = 0;
        for (; i + 4 <= cnt; i += 4) {
#pragma unroll
            for (int u = 0; u < 4; ++u) {
                const int s = __shfl(meta.x, i + u, 64);
                const float w = __int_as_float(__shfl(meta.y, i + u, 64));
                const float2 sv = __bfloat1622float2(S2[(size_t)s * (DIM / 2) + lane]);
                acc.x = fmaf(w, sv.x, acc.x);
                acc.y = fmaf(w, sv.y, acc.y);
            }
        }
        for (; i < cnt; ++i) {
            const int s = __shfl(meta.x, i, 64);
            const float w = __int_as_float(__shfl(meta.y, i, 64));
            const float2 sv = __bfloat1622float2(S2[(size_t)s * (DIM / 2) + lane]);
            acc.x = fmaf(w, sv.x, acc.x);
            acc.y = fmaf(w, sv.y, acc.y);
        }
    }

    ((float2*)(out + (size_t)node * DIM))[lane] = acc;
}

extern "C" void kernel_launch(void* const* d_in, const int* in_sizes, int n_in,
                              void* d_out, int out_size, void* d_ws, size_t ws_size,
                              hipStream_t stream) {
    const float* X    = (const float*)d_in[0];
    const float* W    = (const float*)d_in[1];
    const float* bias = (const float*)d_in[2];
    const float* ew   = (const float*)d_in[3];
    const int*   src  = (const int*)d_in[4];
    const int*   dst  = (const int*)d_in[5];
    float* out = (float*)d_out;

    const int n_nodes = in_sizes[0] / DIM;
    const int n_edges = in_sizes[3];

    // Workspace layout:
    char* ws = (char*)d_ws;
    __hip_bfloat162* S2 = (__hip_bfloat162*)ws;                     // 25.6 MB
    int* counts  = (int*)(ws + (size_t)n_nodes * (DIM / 2) * 4);    // 400 KB
    int* offsets = counts + n_nodes;                                // 400 KB
    int* cursor  = offsets + n_nodes;                               // 400 KB
    int* bsum    = cursor + n_nodes;                                // 4 KB
    int2* edge_sw = (int2*)(bsum + SCAN_B);                         // 12.8 MB

    // 1. GEMM (fp32 compute, bf16 store)
    gemm_xw<<<(n_nodes + 31) / 32, 256, 0, stream>>>(X, W, S2, n_nodes);

    // 2. CSR build
    zero_ints<<<(n_nodes + 255) / 256, 256, 0, stream>>>(counts, n_nodes);
    hist_dst<<<2048, 256, 0, stream>>>(dst, counts, n_edges);

    const int nblocks = (n_nodes + SCAN_B - 1) / SCAN_B;
    scan_block<<<nblocks, SCAN_B, 0, stream>>>(counts, offsets, bsum, n_nodes);
    scan_tops<<<1, SCAN_B, 0, stream>>>(bsum, nblocks);
    scan_fix<<<nblocks, SCAN_B, 0, stream>>>(offsets, bsum, cursor, n_nodes);

    bucket_edges<<<2048, 256, 0, stream>>>(dst, src, ew, cursor, edge_sw, n_edges);

    // 3. Per-node reduction (bias fused, single non-atomic write)
    gcn_reduce<<<(n_nodes + 3) / 4, 256, 0, stream>>>(S2, edge_sw, offsets,
                                                      bias, out, n_nodes, n_edges);
}

// Round 6
// 268.373 us; speedup vs baseline: 5.2861x; 1.3818x over previous
//
#include <hip/hip_runtime.h>
#include <hip/hip_bf16.h>

#define DIM 128

// -------------------- GEMM: support = X @ W, stored as bf16 --------------------
__global__ __launch_bounds__(256) void gemm_xw(const float* __restrict__ X,
                                               const float* __restrict__ W,
                                               __hip_bfloat162* __restrict__ S2,
                                               int n_nodes) {
    __shared__ float4 wlds[DIM * (DIM / 4)];  // 64 KB

    const float4* W4 = (const float4*)W;
    for (int i = threadIdx.x; i < DIM * (DIM / 4); i += 256) wlds[i] = W4[i];
    __syncthreads();

    const int row = blockIdx.x * 32 + (threadIdx.x >> 3);
    const int colg = threadIdx.x & 7;
    if (row >= n_nodes) return;

    const float4* Xr = (const float4*)(X + (size_t)row * DIM);

    float acc[16];
#pragma unroll
    for (int i = 0; i < 16; ++i) acc[i] = 0.0f;

    for (int k4 = 0; k4 < DIM / 4; ++k4) {
        const float4 xv = Xr[k4];
        const float xs[4] = {xv.x, xv.y, xv.z, xv.w};
#pragma unroll
        for (int kk = 0; kk < 4; ++kk) {
            const int k = k4 * 4 + kk;
            const float x = xs[kk];
            const float4* wr = &wlds[k * (DIM / 4) + colg * 4];
#pragma unroll
            for (int c = 0; c < 4; ++c) {
                const float4 wv = wr[c];
                acc[c * 4 + 0] = fmaf(x, wv.x, acc[c * 4 + 0]);
                acc[c * 4 + 1] = fmaf(x, wv.y, acc[c * 4 + 1]);
                acc[c * 4 + 2] = fmaf(x, wv.z, acc[c * 4 + 2]);
                acc[c * 4 + 3] = fmaf(x, wv.w, acc[c * 4 + 3]);
            }
        }
    }

    __hip_bfloat162* Sr = S2 + (size_t)row * (DIM / 2) + colg * 8;
#pragma unroll
    for (int c = 0; c < 8; ++c) {
        float2 f = {acc[2 * c], acc[2 * c + 1]};
        Sr[c] = __float22bfloat162_rn(f);
    }
}

// -------------------- CSR build --------------------
__global__ __launch_bounds__(256) void zero_ints(int* __restrict__ p, int n) {
    const int i = blockIdx.x * 256 + threadIdx.x;
    if (i < n) p[i] = 0;
}

// Histogram of dst; ALSO records each edge's arrival rank within its dst bucket.
// The rank is the atomicAdd return value — free, and it lets the bucket pass
// run with no atomics at all.
__global__ __launch_bounds__(256) void hist_rank(const int* __restrict__ dst,
                                                 int* __restrict__ counts,
                                                 int* __restrict__ rank,
                                                 int n_edges) {
    for (int e = blockIdx.x * 256 + threadIdx.x; e < n_edges; e += gridDim.x * 256)
        rank[e] = atomicAdd(&counts[dst[e]], 1);
}

#define SCAN_B 1024
__global__ __launch_bounds__(SCAN_B) void scan_block(const int* __restrict__ counts,
                                                     int* __restrict__ offsets,
                                                     int* __restrict__ bsum,
                                                     int n) {
    __shared__ int lds[SCAN_B];
    const int i = blockIdx.x * SCAN_B + threadIdx.x;
    int v = (i < n) ? counts[i] : 0;
    const int own = v;
    lds[threadIdx.x] = v;
    __syncthreads();
#pragma unroll
    for (int off = 1; off < SCAN_B; off <<= 1) {
        int t = (threadIdx.x >= off) ? lds[threadIdx.x - off] : 0;
        __syncthreads();
        lds[threadIdx.x] += t;
        __syncthreads();
    }
    if (i < n) offsets[i] = lds[threadIdx.x] - own;  // exclusive
    if (threadIdx.x == SCAN_B - 1) bsum[blockIdx.x] = lds[threadIdx.x];
}

// Parallel exclusive scan of block sums (single block; nblocks <= 1024).
__global__ __launch_bounds__(SCAN_B) void scan_tops(int* __restrict__ bsum, int nblocks) {
    __shared__ int lds[SCAN_B];
    int v = (threadIdx.x < nblocks) ? bsum[threadIdx.x] : 0;
    const int own = v;
    lds[threadIdx.x] = v;
    __syncthreads();
#pragma unroll
    for (int off = 1; off < SCAN_B; off <<= 1) {
        int t = (threadIdx.x >= off) ? lds[threadIdx.x - off] : 0;
        __syncthreads();
        lds[threadIdx.x] += t;
        __syncthreads();
    }
    if (threadIdx.x < nblocks) bsum[threadIdx.x] = lds[threadIdx.x] - own;
}

__global__ __launch_bounds__(SCAN_B) void scan_fix(int* __restrict__ offsets,
                                                   const int* __restrict__ bsum,
                                                   int n) {
    const int i = blockIdx.x * SCAN_B + threadIdx.x;
    if (i < n) offsets[i] += bsum[blockIdx.x];
}

// Scatter {src, weight-bits} into dst-sorted position. pos = offsets[dst]+rank:
// unique by construction, NO atomic — store latency fully hides.
__global__ __launch_bounds__(256) void bucket_edges(const int* __restrict__ dst,
                                                    const int* __restrict__ src,
                                                    const float* __restrict__ ew,
                                                    const int* __restrict__ offsets,
                                                    const int* __restrict__ rank,
                                                    int2* __restrict__ edge_sw,
                                                    int n_edges) {
    for (int e = blockIdx.x * 256 + threadIdx.x; e < n_edges; e += gridDim.x * 256) {
        const int pos = offsets[dst[e]] + rank[e];
        edge_sw[pos] = make_int2(src[e], __float_as_int(ew[e]));
    }
}

// -------------------- reduce: out[n] = bias + sum ew*S[src] --------------------
// One wave per node. Lane l preloads edge (start+l)'s {src,w} (coalesced), inner
// loop broadcasts via shfl; 8x unroll keeps 8 independent S-row gathers in flight.
__global__ __launch_bounds__(256) void gcn_reduce(const __hip_bfloat162* __restrict__ S2,
                                                  const int2* __restrict__ edge_sw,
                                                  const int* __restrict__ offsets,
                                                  const float* __restrict__ bias,
                                                  float* __restrict__ out,
                                                  int n_nodes, int n_edges) {
    const int node = blockIdx.x * 4 + (threadIdx.x >> 6);
    if (node >= n_nodes) return;
    const int lane = threadIdx.x & 63;

    const int start = offsets[node];
    const int end = (node + 1 < n_nodes) ? offsets[node + 1] : n_edges;

    float2 acc = ((const float2*)bias)[lane];

    for (int base = start; base < end; base += 64) {
        const int cnt = min(64, end - base);
        int2 meta = make_int2(0, 0);
        if (lane < cnt) meta = edge_sw[base + lane];

        int i = 0;
        for (; i + 8 <= cnt; i += 8) {
            float2 sv[8];
#pragma unroll
            for (int u = 0; u < 8; ++u) {
                const int s = __shfl(meta.x, i + u, 64);
                sv[u] = __bfloat1622float2(S2[(size_t)s * (DIM / 2) + lane]);
            }
#pragma unroll
            for (int u = 0; u < 8; ++u) {
                const float w = __int_as_float(__shfl(meta.y, i + u, 64));
                acc.x = fmaf(w, sv[u].x, acc.x);
                acc.y = fmaf(w, sv[u].y, acc.y);
            }
        }
        for (; i < cnt; ++i) {
            const int s = __shfl(meta.x, i, 64);
            const float w = __int_as_float(__shfl(meta.y, i, 64));
            const float2 sv = __bfloat1622float2(S2[(size_t)s * (DIM / 2) + lane]);
            acc.x = fmaf(w, sv.x, acc.x);
            acc.y = fmaf(w, sv.y, acc.y);
        }
    }

    ((float2*)(out + (size_t)node * DIM))[lane] = acc;
}

extern "C" void kernel_launch(void* const* d_in, const int* in_sizes, int n_in,
                              void* d_out, int out_size, void* d_ws, size_t ws_size,
                              hipStream_t stream) {
    const float* X    = (const float*)d_in[0];
    const float* W    = (const float*)d_in[1];
    const float* bias = (const float*)d_in[2];
    const float* ew   = (const float*)d_in[3];
    const int*   src  = (const int*)d_in[4];
    const int*   dst  = (const int*)d_in[5];
    float* out = (float*)d_out;

    const int n_nodes = in_sizes[0] / DIM;
    const int n_edges = in_sizes[3];

    // Workspace layout:
    char* ws = (char*)d_ws;
    __hip_bfloat162* S2 = (__hip_bfloat162*)ws;                     // 25.6 MB
    int* counts  = (int*)(ws + (size_t)n_nodes * (DIM / 2) * 4);    // 400 KB
    int* offsets = counts + n_nodes;                                // 400 KB
    int* bsum    = offsets + n_nodes;                               // 4 KB
    int* rank    = bsum + SCAN_B;                                   // 6.4 MB
    int2* edge_sw = (int2*)(rank + n_edges);                        // 12.8 MB

    // 1. GEMM (fp32 compute, bf16 store)
    gemm_xw<<<(n_nodes + 31) / 32, 256, 0, stream>>>(X, W, S2, n_nodes);

    // 2. CSR build
    zero_ints<<<(n_nodes + 255) / 256, 256, 0, stream>>>(counts, n_nodes);
    hist_rank<<<2048, 256, 0, stream>>>(dst, counts, rank, n_edges);

    const int nblocks = (n_nodes + SCAN_B - 1) / SCAN_B;
    scan_block<<<nblocks, SCAN_B, 0, stream>>>(counts, offsets, bsum, n_nodes);
    scan_tops<<<1, SCAN_B, 0, stream>>>(bsum, nblocks);
    scan_fix<<<nblocks, SCAN_B, 0, stream>>>(offsets, bsum, n_nodes);

    bucket_edges<<<2048, 256, 0, stream>>>(dst, src, ew, offsets, rank,
                                           edge_sw, n_edges);

    // 3. Per-node reduction (bias fused, single non-atomic write)
    gcn_reduce<<<(n_nodes + 3) / 4, 256, 0, stream>>>(S2, edge_sw, offsets,
                                                      bias, out, n_nodes, n_edges);
}

// Round 7
// 190.119 us; speedup vs baseline: 7.4618x; 1.4116x over previous
//
#include <hip/hip_runtime.h>
#include <hip/hip_bf16.h>

#define DIM 128

typedef short short8 __attribute__((ext_vector_type(8)));
typedef float f32x4 __attribute__((ext_vector_type(4)));

static __device__ __forceinline__ unsigned short f2bf(float f) {
    unsigned u = __builtin_bit_cast(unsigned, f);
    unsigned r = (u + 0x7fffu + ((u >> 16) & 1u)) >> 16;  // RNE
    return (unsigned short)r;
}

// -------------------- GEMM: S2 = bf16(X @ W) via MFMA --------------------
// Block = 256 threads (4 waves), BM = 64 rows. W staged to LDS as bf16,
// transposed [n][k] with XOR swizzle (k ^ (n&7)<<3) for bank spread.
// Per wave: 16 rows x 128 cols = 8 col-tiles x 4 k-steps of 16x16x32 MFMA.
// A/B fragments use the SAME k-slot packing (permutation-invariant in k);
// m = lane&15 (A), n = lane&15 (B); C/D: col=lane&15, row=(lane>>4)*4+reg.
__global__ __launch_bounds__(256) void gemm_xw_mfma(const float* __restrict__ X,
                                                    const float* __restrict__ W,
                                                    unsigned short* __restrict__ S2,
                                                    int n_nodes) {
    __shared__ unsigned short wlds[DIM * DIM];  // 32 KB, swizzled W^T bf16

    // Stage W: W[k][n] fp32 -> wlds[n*128 + (k ^ ((n&7)<<3))] bf16
    for (int idx = threadIdx.x; idx < DIM * DIM; idx += 256) {
        const int k = idx >> 7;
        const int n = idx & 127;
        wlds[n * DIM + (k ^ ((n & 7) << 3))] = f2bf(W[idx]);
    }
    __syncthreads();

    const int wave = threadIdx.x >> 6;
    const int lane = threadIdx.x & 63;
    const int row_base = blockIdx.x * 64 + wave * 16;
    const int mrow = lane & 15;
    const int kq = lane >> 4;           // 0..3
    const int kq8 = kq * 8;

    // A: lane holds rows row_base+mrow, k-slots kq8..kq8+7 of each 32-k step.
    int rr = row_base + mrow;
    if (rr >= n_nodes) rr = n_nodes - 1;  // clamp (stores are guarded)
    const float4* Xr = (const float4*)(X + (size_t)rr * DIM);

    short8 a[4];
#pragma unroll
    for (int s = 0; s < 4; ++s) {
        const float4 v0 = Xr[s * 8 + kq * 2];
        const float4 v1 = Xr[s * 8 + kq * 2 + 1];
        short8 av;
        av[0] = f2bf(v0.x); av[1] = f2bf(v0.y); av[2] = f2bf(v0.z); av[3] = f2bf(v0.w);
        av[4] = f2bf(v1.x); av[5] = f2bf(v1.y); av[6] = f2bf(v1.z); av[7] = f2bf(v1.w);
        a[s] = av;
    }

    f32x4 acc[8];
#pragma unroll
    for (int c = 0; c < 8; ++c) acc[c] = (f32x4){0.f, 0.f, 0.f, 0.f};

    const int swz = (lane & 7) << 3;
#pragma unroll
    for (int s = 0; s < 4; ++s) {
        const int k0 = s * 32 + kq8;
#pragma unroll
        for (int c = 0; c < 8; ++c) {
            const int n = c * 16 + mrow;
            const short8 bv = *(const short8*)(&wlds[n * DIM + (k0 ^ swz)]);
            acc[c] = __builtin_amdgcn_mfma_f32_16x16x32_bf16(a[s], bv, acc[c], 0, 0, 0);
        }
    }

    // C/D: col = lane&15, row = kq*4 + reg
#pragma unroll
    for (int reg = 0; reg < 4; ++reg) {
        const int g_r = row_base + kq * 4 + reg;
        if (g_r < n_nodes) {
            unsigned short* orow = S2 + (size_t)g_r * DIM + mrow;
#pragma unroll
            for (int c = 0; c < 8; ++c) orow[c * 16] = f2bf(acc[c][reg]);
        }
    }
}

// -------------------- CSR build --------------------
__global__ __launch_bounds__(256) void zero_ints(int* __restrict__ p, int n) {
    const int i = blockIdx.x * 256 + threadIdx.x;
    if (i < n) p[i] = 0;
}

// Histogram of dst; rank = atomicAdd return value (edge's slot in its bucket).
__global__ __launch_bounds__(256) void hist_rank(const int* __restrict__ dst,
                                                 int* __restrict__ counts,
                                                 int* __restrict__ rank,
                                                 int n_edges) {
    for (int e = blockIdx.x * 256 + threadIdx.x; e < n_edges; e += gridDim.x * 256)
        rank[e] = atomicAdd(&counts[dst[e]], 1);
}

#define SCAN_B 1024
__global__ __launch_bounds__(SCAN_B) void scan_block(const int* __restrict__ counts,
                                                     int* __restrict__ offsets,
                                                     int* __restrict__ bsum,
                                                     int n) {
    __shared__ int lds[SCAN_B];
    const int i = blockIdx.x * SCAN_B + threadIdx.x;
    int v = (i < n) ? counts[i] : 0;
    const int own = v;
    lds[threadIdx.x] = v;
    __syncthreads();
#pragma unroll
    for (int off = 1; off < SCAN_B; off <<= 1) {
        int t = (threadIdx.x >= off) ? lds[threadIdx.x - off] : 0;
        __syncthreads();
        lds[threadIdx.x] += t;
        __syncthreads();
    }
    if (i < n) offsets[i] = lds[threadIdx.x] - own;  // exclusive
    if (threadIdx.x == SCAN_B - 1) bsum[blockIdx.x] = lds[threadIdx.x];
}

__global__ __launch_bounds__(SCAN_B) void scan_tops(int* __restrict__ bsum, int nblocks) {
    __shared__ int lds[SCAN_B];
    int v = (threadIdx.x < nblocks) ? bsum[threadIdx.x] : 0;
    const int own = v;
    lds[threadIdx.x] = v;
    __syncthreads();
#pragma unroll
    for (int off = 1; off < SCAN_B; off <<= 1) {
        int t = (threadIdx.x >= off) ? lds[threadIdx.x - off] : 0;
        __syncthreads();
        lds[threadIdx.x] += t;
        __syncthreads();
    }
    if (threadIdx.x < nblocks) bsum[threadIdx.x] = lds[threadIdx.x] - own;
}

__global__ __launch_bounds__(SCAN_B) void scan_fix(int* __restrict__ offsets,
                                                   const int* __restrict__ bsum,
                                                   int n) {
    const int i = blockIdx.x * SCAN_B + threadIdx.x;
    if (i < n) offsets[i] += bsum[blockIdx.x];
}

// Atomic-free scatter: pos = offsets[dst] + rank (unique by construction).
__global__ __launch_bounds__(256) void bucket_edges(const int* __restrict__ dst,
                                                    const int* __restrict__ src,
                                                    const float* __restrict__ ew,
                                                    const int* __restrict__ offsets,
                                                    const int* __restrict__ rank,
                                                    int2* __restrict__ edge_sw,
                                                    int n_edges) {
    for (int e = blockIdx.x * 256 + threadIdx.x; e < n_edges; e += gridDim.x * 256) {
        const int pos = offsets[dst[e]] + rank[e];
        edge_sw[pos] = make_int2(src[e], __float_as_int(ew[e]));
    }
}

// -------------------- reduce: out[n] = bias + sum ew*S[src] --------------------
__global__ __launch_bounds__(256) void gcn_reduce(const __hip_bfloat162* __restrict__ S2,
                                                  const int2* __restrict__ edge_sw,
                                                  const int* __restrict__ offsets,
                                                  const float* __restrict__ bias,
                                                  float* __restrict__ out,
                                                  int n_nodes, int n_edges) {
    const int node = blockIdx.x * 4 + (threadIdx.x >> 6);
    if (node >= n_nodes) return;
    const int lane = threadIdx.x & 63;

    const int start = offsets[node];
    const int end = (node + 1 < n_nodes) ? offsets[node + 1] : n_edges;

    float2 acc = ((const float2*)bias)[lane];

    for (int base = start; base < end; base += 64) {
        const int cnt = min(64, end - base);
        int2 meta = make_int2(0, 0);
        if (lane < cnt) meta = edge_sw[base + lane];

        int i = 0;
        for (; i + 8 <= cnt; i += 8) {
            float2 sv[8];
#pragma unroll
            for (int u = 0; u < 8; ++u) {
                const int s = __shfl(meta.x, i + u, 64);
                sv[u] = __bfloat1622float2(S2[(size_t)s * (DIM / 2) + lane]);
            }
#pragma unroll
            for (int u = 0; u < 8; ++u) {
                const float w = __int_as_float(__shfl(meta.y, i + u, 64));
                acc.x = fmaf(w, sv[u].x, acc.x);
                acc.y = fmaf(w, sv[u].y, acc.y);
            }
        }
        for (; i < cnt; ++i) {
            const int s = __shfl(meta.x, i, 64);
            const float w = __int_as_float(__shfl(meta.y, i, 64));
            const float2 sv = __bfloat1622float2(S2[(size_t)s * (DIM / 2) + lane]);
            acc.x = fmaf(w, sv.x, acc.x);
            acc.y = fmaf(w, sv.y, acc.y);
        }
    }

    ((float2*)(out + (size_t)node * DIM))[lane] = acc;
}

extern "C" void kernel_launch(void* const* d_in, const int* in_sizes, int n_in,
                              void* d_out, int out_size, void* d_ws, size_t ws_size,
                              hipStream_t stream) {
    const float* X    = (const float*)d_in[0];
    const float* W    = (const float*)d_in[1];
    const float* bias = (const float*)d_in[2];
    const float* ew   = (const float*)d_in[3];
    const int*   src  = (const int*)d_in[4];
    const int*   dst  = (const int*)d_in[5];
    float* out = (float*)d_out;

    const int n_nodes = in_sizes[0] / DIM;
    const int n_edges = in_sizes[3];

    // Workspace layout:
    char* ws = (char*)d_ws;
    __hip_bfloat162* S2 = (__hip_bfloat162*)ws;                     // 25.6 MB
    int* counts  = (int*)(ws + (size_t)n_nodes * (DIM / 2) * 4);    // 400 KB
    int* offsets = counts + n_nodes;                                // 400 KB
    int* bsum    = offsets + n_nodes;                               // 4 KB
    int* rank    = bsum + SCAN_B;                                   // 6.4 MB
    int2* edge_sw = (int2*)(rank + n_edges);                        // 12.8 MB

    // 1. GEMM (bf16 MFMA, fp32 accumulate, bf16 store)
    gemm_xw_mfma<<<(n_nodes + 63) / 64, 256, 0, stream>>>(X, W,
                                                          (unsigned short*)S2, n_nodes);

    // 2. CSR build
    zero_ints<<<(n_nodes + 255) / 256, 256, 0, stream>>>(counts, n_nodes);
    hist_rank<<<2048, 256, 0, stream>>>(dst, counts, rank, n_edges);

    const int nblocks = (n_nodes + SCAN_B - 1) / SCAN_B;
    scan_block<<<nblocks, SCAN_B, 0, stream>>>(counts, offsets, bsum, n_nodes);
    scan_tops<<<1, SCAN_B, 0, stream>>>(bsum, nblocks);
    scan_fix<<<nblocks, SCAN_B, 0, stream>>>(offsets, bsum, n_nodes);

    bucket_edges<<<2048, 256, 0, stream>>>(dst, src, ew, offsets, rank,
                                           edge_sw, n_edges);

    // 3. Per-node reduction (bias fused, single non-atomic write)
    gcn_reduce<<<(n_nodes + 3) / 4, 256, 0, stream>>>(S2, edge_sw, offsets,
                                                      bias, out, n_nodes, n_edges);
}